// Round 4
// baseline (2192.982 us; speedup 1.0000x reference)
//
#include <hip/hip_runtime.h>
#include <hip/hip_bf16.h>

typedef __hip_bfloat16 bf16;
typedef __attribute__((ext_vector_type(8))) short short8;
typedef __attribute__((ext_vector_type(4))) float f32x4;

static constexpr int Bz = 16, Sq = 512, Lw = 12, Dm = 512, Hh = 8, DFFd = 2048, Vv = 631;
static constexpr int Mtok = Bz * Sq;   // 8192
static constexpr int VPAD = 640;       // 631 padded to /128
static constexpr int QKS = 1024;       // qkv buffer row stride (q 0-511, k 512-1023; v -> vt)
static constexpr int NCNT = 24 * 32;   // ticket counters: 12 layers x 2 fused GEMMs x 32 bm

__device__ __forceinline__ bf16 f2b(float x) { return __float2bfloat16(x); }
__device__ __forceinline__ float bfu(unsigned short s) {
    union { unsigned u; float f; } c; c.u = (unsigned)s << 16; return c.f;
}

__device__ __forceinline__ f32x4 z4() { f32x4 v; v[0]=0.f; v[1]=0.f; v[2]=0.f; v[3]=0.f; return v; }

__device__ __forceinline__ void gload_lds16(const bf16* g, bf16* l) {
    __builtin_amdgcn_global_load_lds(
        (const __attribute__((address_space(1))) unsigned int*)(g),
        (__attribute__((address_space(3))) unsigned int*)(l),
        16, 0, 0);
}

// ---------------- sin/cos tables: [S][32] + zero the LN ticket counters ----------------
__global__ void k_sincos(float* __restrict__ cosT, float* __restrict__ sinT, int* __restrict__ cnt) {
    int i = blockIdx.x * 256 + threadIdx.x;            // S*32 = 16384
    if (i < NCNT) cnt[i] = 0;
    int s = i >> 5, f = i & 31;
    float inv = powf(10000.0f, -(float)(2 * f) / 64.0f);
    float t = (float)s * inv;
    sinT[i] = sinf(t);
    cosT[i] = cosf(t);
}

// ---------------- emb -> bf16 padded [VPAD][512] (B^T for final GEMM) ----------------
__global__ void k_embconv(const float* __restrict__ emb, bf16* __restrict__ embT) {
    int i = blockIdx.x * 256 + threadIdx.x;            // VPAD*512
    int n = i >> 9;
    embT[i] = (n < Vv) ? f2b(emb[i]) : f2b(0.0f);
}

// ---------------- h = emb[data] + pos ----------------
__global__ void k_embed(const int* __restrict__ data, const float* __restrict__ emb,
                        const float* __restrict__ pos, float* __restrict__ hf, bf16* __restrict__ hb) {
    int tok = blockIdx.x;
    int id = data[tok];
    int s = tok & (Sq - 1);
    for (int d = threadIdx.x; d < Dm; d += 256) {
        float v = emb[id * Dm + d] + pos[s * Dm + d];
        hf[(size_t)tok * Dm + d] = v;
        hb[(size_t)tok * Dm + d] = f2b(v);
    }
}

// ---------------- weight transpose+convert: src f32 [K][N] -> dst bf16 [N][K] ----------------
__global__ void k_wtrans(const float* __restrict__ src, bf16* __restrict__ dst,
                         int K, int N, long long sStride, long long dStride) {
    src += (long long)blockIdx.z * sStride;
    dst += (long long)blockIdx.z * dStride;
    __shared__ float tile[32][33];
    int k0 = blockIdx.y * 32, n0 = blockIdx.x * 32;
    int tx = threadIdx.x & 31, ty = threadIdx.x >> 5;  // ty 0..7
    #pragma unroll
    for (int r = ty; r < 32; r += 8) tile[r][tx] = src[(size_t)(k0 + r) * N + n0 + tx];
    __syncthreads();
    #pragma unroll
    for (int r = ty; r < 32; r += 8) dst[(size_t)(n0 + r) * K + k0 + tx] = f2b(tile[tx][r]);
}

// ================= WIDE GEMM: BM=256, BN=128, BK=32, 8 waves, 3-deep LDS ring ==========
// 72KB dynamic LDS -> 2 blocks/CU. Counted vmcnt(3) per iter (tile kt landed, kt+1 in
// flight ACROSS the raw s_barrier). STAGE(kt+2) post-barrier overwrites buf[kt-1] whose
// reads retired pre-barrier. 64B-row swizzle: chunk XOR (row>>1)&3 (2-way max = free).
// XCD swizzle. gridDim.z = split-K.
// EPI: 1 = split-K=2 bf16 partials + FUSED add&LN (ticket: 8 blocks per bm row-group
//          -> each does 32 rows of LN after all partials land; grid is exactly 256
//          blocks <= 1 block/CU x 256 CUs co-resident => spin is deadlock-free);
//      2 = +bias,relu,bf16; 3 = +bias, f32 out [M][Vv] col-guarded (vocab);
//      4 = qkv: RoPE'd q(x0.125)|k -> Cout[M][1024], v-cols -> vt (Cout2) transposed
template<int EPI>
__global__ __launch_bounds__(512) void k_gemmW(const bf16* __restrict__ A, const bf16* __restrict__ Bt,
                                               void* __restrict__ Cout, void* __restrict__ Cout2,
                                               const float* __restrict__ bias,
                                               const float* __restrict__ cosT, const float* __restrict__ sinT,
                                               int M, int N, int K, int ldA, int ldB,
                                               float* __restrict__ hfp, bf16* __restrict__ hbp,
                                               const float* __restrict__ gamma, const float* __restrict__ beta,
                                               int* __restrict__ cnt) {
    extern __shared__ __align__(16) char smem[];
    bf16* lAbase = (bf16*)smem;                        // 3 x 256*32
    bf16* lBbase = (bf16*)(smem + 3 * 256 * 32 * 2);   // 3 x 128*32

    const int t = threadIdx.x;                 // 0..511
    const int lane = t & 63;
    const int wave = t >> 6;                   // 0..7
    const int wr = wave >> 1, wc = wave & 1;   // 4 x 2 wave grid
    const int l15 = lane & 15, l4 = lane >> 4;

    // XCD swizzle over linearized 3D grid (nwg % 8 == 0 for all launches here)
    const int gx = gridDim.x, gy = gridDim.y;
    const int nwg = gx * gy * gridDim.z;
    const int cpx = nwg >> 3;
    int lin = (blockIdx.z * gy + blockIdx.y) * gx + blockIdx.x;
    lin = (lin & 7) * cpx + (lin >> 3);
    const int bn = lin % gx;
    const int rem = lin / gx;
    const int bm = rem % gy;
    const int bz = rem / gy;

    const bf16* Ab = A + (size_t)(bm * 256) * ldA + (size_t)bz * K;
    const bf16* Bb = Bt + (size_t)(bn * 128) * ldB + (size_t)bz * K;

    // staging maps: 16B chunk q -> row r = q>>2, phys slot s = q&3 holds logical s^((r>>1)&3)
    int soffA[2], soffB0;
    #pragma unroll
    for (int p = 0; p < 2; p++) {
        int q = p * 512 + t, r = q >> 2, s = q & 3;
        soffA[p] = r * ldA + ((s ^ ((r >> 1) & 3)) << 3);
    }
    {
        int r = t >> 2, s = t & 3;
        soffB0 = r * ldB + ((s ^ ((r >> 1) & 3)) << 3);
    }

    f32x4 acc[4][4];
    #pragma unroll
    for (int i = 0; i < 4; i++)
        #pragma unroll
        for (int j = 0; j < 4; j++) acc[i][j] = z4();

    auto STAGE = [&](int buf, int kt) {         // 3 gload_lds per thread
        const int k0 = kt << 5;
        bf16* la = lAbase + buf * (256 * 32);
        bf16* lb = lBbase + buf * (128 * 32);
        #pragma unroll
        for (int p = 0; p < 2; p++)
            gload_lds16(Ab + (size_t)soffA[p] + k0, &la[(p * 512 + t) * 8]);
        gload_lds16(Bb + (size_t)soffB0 + k0, &lb[t * 8]);
    };

    auto COMPUTE = [&](int buf) {               // one BK=32 slice: 16 MFMA/wave
        const char* la = (const char*)(lAbase + buf * (256 * 32));
        const char* lb = (const char*)(lBbase + buf * (128 * 32));
        short8 af[4], bfr[4];
        #pragma unroll
        for (int i = 0; i < 4; i++) {
            int row = wr * 64 + i * 16 + l15;
            af[i] = *(const short8*)(la + row * 64 + (((l4 ^ (row >> 1)) & 3) << 4));
        }
        #pragma unroll
        for (int j = 0; j < 4; j++) {
            int row = wc * 64 + j * 16 + l15;
            bfr[j] = *(const short8*)(lb + row * 64 + (((l4 ^ (row >> 1)) & 3) << 4));
        }
        #pragma unroll
        for (int i = 0; i < 4; i++)
            #pragma unroll
            for (int j = 0; j < 4; j++)
                acc[i][j] = __builtin_amdgcn_mfma_f32_16x16x32_bf16(af[i], bfr[j], acc[i][j], 0, 0, 0);
    };

    const int nk = K >> 5;
    STAGE(0, 0);
    STAGE(1, 1);
    int kt = 0;
    for (; kt < nk - 1; ++kt) {
        asm volatile("s_waitcnt vmcnt(3)" ::: "memory");   // tile kt landed; kt+1 in flight
        __builtin_amdgcn_s_barrier();
        if (kt + 2 < nk) STAGE((kt + 2) % 3, kt + 2);
        __builtin_amdgcn_s_setprio(1);
        COMPUTE(kt % 3);
        __builtin_amdgcn_s_setprio(0);
    }
    asm volatile("s_waitcnt vmcnt(0)" ::: "memory");
    __builtin_amdgcn_s_barrier();
    __builtin_amdgcn_s_setprio(1);
    COMPUTE(kt % 3);
    __builtin_amdgcn_s_setprio(0);

    // ---- epilogue ----
    #pragma unroll
    for (int i = 0; i < 4; i++) {
        #pragma unroll
        for (int j = 0; j < 4; j++) {
            const int col = bn * 128 + wc * 64 + j * 16 + l15;
            const int row0 = bm * 256 + wr * 64 + i * 16 + l4 * 4;
            if (EPI == 4 && col >= 1024) {
                // v columns -> vt[bh][d][s], 4 consecutive s packed as 8B
                int h = (col - 1024) >> 6, d = (col - 1024) & 63;
                int b = row0 >> 9, s0 = row0 & 511;
                bf16 pk[4];
                #pragma unroll
                for (int r = 0; r < 4; r++) pk[r] = f2b(acc[i][j][r]);
                *(ushort4*)&((bf16*)Cout2)[((size_t)(b * 8 + h) * 64 + d) * 512 + s0] =
                    *(const ushort4*)pk;
                continue;
            }
            #pragma unroll
            for (int r = 0; r < 4; r++) {
                int row = row0 + r;
                float v = acc[i][j][r];
                if (EPI == 1) {
                    // split-K partial slab bz
                    ((bf16*)Cout)[(size_t)bz * ((size_t)M * N) + (size_t)row * N + col] = f2b(v);
                } else if (EPI == 2) {
                    v += bias[col];
                    v = v > 0.f ? v : 0.f;
                    ((bf16*)Cout)[(size_t)row * N + col] = f2b(v);
                } else if (EPI == 3) {
                    if (col < Vv) ((float*)Cout)[(size_t)row * Vv + col] = v + bias[col];
                } else {
                    // EPI 4, col < 1024: RoPE on q (scaled 1/8) and k
                    float p = __shfl_xor(v, 1, 64);   // partner column col^1, same row
                    int srow = row & (Sq - 1);
                    int f = (col >> 1) & 31;
                    float cc = cosT[srow * 32 + f], sn = sinT[srow * 32 + f];
                    float o = (col & 1) ? (v * cc + p * sn) : (v * cc - p * sn);
                    if (col < 512) o *= 0.125f;
                    ((bf16*)Cout)[(size_t)row * QKS + col] = f2b(o);
                }
            }
        }
    }

    // ---- fused add&LN (EPI==1 only): ticket over the 8 blocks (4 bn x 2 bz) of this bm ----
    if (EPI == 1) {
        __syncthreads();                              // all epilogue stores drained (vmcnt0 at barrier)
        if (t == 0) {
            // release: writes back this XCD's dirty L2 so other XCDs see the partials
            __hip_atomic_fetch_add(cnt + bm, 1, __ATOMIC_ACQ_REL, __HIP_MEMORY_SCOPE_AGENT);
            while (__hip_atomic_load(cnt + bm, __ATOMIC_RELAXED, __HIP_MEMORY_SCOPE_AGENT) < 8)
                __builtin_amdgcn_s_sleep(2);
        }
        __syncthreads();
        __builtin_amdgcn_fence(__ATOMIC_ACQUIRE, "agent");   // invalidate stale caches before reading partials
        const bf16* part = (const bf16*)Cout;
        const size_t pstr = (size_t)M * N;
        const int wv = t >> 6, lx = t & 63;
        const int r0 = bm * 256 + (bz * 4 + bn) * 32 + wv * 4;   // this block's 32-row share
        #pragma unroll
        for (int rr = 0; rr < 4; rr++) {
            const int row = r0 + rr;
            const size_t base = (size_t)row * N + lx * 8;
            float v[8];
            float4 h0 = *(const float4*)&hfp[base];
            float4 h1 = *(const float4*)&hfp[base + 4];
            short8 p0 = *(const short8*)&part[base];
            short8 p1 = *(const short8*)&part[base + pstr];
            v[0] = h0.x; v[1] = h0.y; v[2] = h0.z; v[3] = h0.w;
            v[4] = h1.x; v[5] = h1.y; v[6] = h1.z; v[7] = h1.w;
            #pragma unroll
            for (int k = 0; k < 8; k++)
                v[k] += bfu((unsigned short)p0[k]) + bfu((unsigned short)p1[k]);
            if (bias) {
                float4 b0 = *(const float4*)&bias[lx * 8];
                float4 b1 = *(const float4*)&bias[lx * 8 + 4];
                v[0] += b0.x; v[1] += b0.y; v[2] += b0.z; v[3] += b0.w;
                v[4] += b1.x; v[5] += b1.y; v[6] += b1.z; v[7] += b1.w;
            }
            float s = 0.f, sq = 0.f;
            #pragma unroll
            for (int k = 0; k < 8; k++) { s += v[k]; sq += v[k] * v[k]; }
            #pragma unroll
            for (int m2 = 1; m2 < 64; m2 <<= 1) { s += __shfl_xor(s, m2, 64); sq += __shfl_xor(sq, m2, 64); }
            float mean = s * (1.f / 512.f);           // N==512 for both fused GEMMs
            float var = sq * (1.f / 512.f) - mean * mean;
            float inv = rsqrtf(var + 1e-5f);
            float4 g0 = *(const float4*)&gamma[lx * 8];
            float4 g1 = *(const float4*)&gamma[lx * 8 + 4];
            float4 e0 = *(const float4*)&beta[lx * 8];
            float4 e1 = *(const float4*)&beta[lx * 8 + 4];
            float gs[8] = {g0.x, g0.y, g0.z, g0.w, g1.x, g1.y, g1.z, g1.w};
            float es[8] = {e0.x, e0.y, e0.z, e0.w, e1.x, e1.y, e1.z, e1.w};
            float ov[8];
            short8 ob;
            #pragma unroll
            for (int k = 0; k < 8; k++) {
                ov[k] = (v[k] - mean) * inv * gs[k] + es[k];
                ob[k] = (short)__bfloat16_as_ushort(f2b(ov[k]));
            }
            float4 o0; o0.x = ov[0]; o0.y = ov[1]; o0.z = ov[2]; o0.w = ov[3];
            float4 o1; o1.x = ov[4]; o1.y = ov[5]; o1.z = ov[6]; o1.w = ov[7];
            *(float4*)&hfp[base] = o0;
            *(float4*)&hfp[base + 4] = o1;
            *(short8*)&hbp[base] = ob;
        }
    }
}

// ---------------- causal flash attention: 8 waves x 16 q-rows (QBLK=128), KV tiles of 64 ----
// double-buffered K/V LDS (one raw s_barrier per tile, vmcnt NOT drained -> next tile's
// global loads stay in flight under compute); lP padded to 88; waves skip fully-masked tiles.
__global__ __launch_bounds__(512) void k_attn(const bf16* __restrict__ qkv,
                                              const bf16* __restrict__ vt, bf16* __restrict__ av) {
    __shared__ __align__(16) bf16 lK[2][64][80];
    __shared__ __align__(16) bf16 lV[2][64][80];
    __shared__ __align__(16) bf16 lP[8][16][88];
    const int tq = blockIdx.x, bh = blockIdx.y;
    const int b = bh >> 3, h = bh & 7;
    const int t = threadIdx.x, lane = t & 63, w = t >> 6;   // w 0..7
    const int l15 = lane & 15, l4 = lane >> 4;
    const int q0 = tq * 128;
    const int rowb = q0 + w * 16;                 // wave's first q-row

    short8 qf[2];
    {
        const bf16* qr = qkv + (size_t)(b * Sq + rowb + l15) * QKS + h * 64 + l4 * 8;
        qf[0] = *(const short8*)qr;
        qf[1] = *(const short8*)(qr + 32);
    }
    f32x4 o[4];
    #pragma unroll
    for (int j = 0; j < 4; j++) o[j] = z4();
    float mrow[4] = {-1e30f, -1e30f, -1e30f, -1e30f};
    float ssum[4] = {0.f, 0.f, 0.f, 0.f};

    const int nk = (q0 >> 6) + 2;                 // KV tiles covering rows [q0, q0+128)
    const int sr = t >> 3, scc = (t & 7) * 8;     // 512 threads x 16B = full 64x64 tile
    const bf16* gK = qkv + (size_t)(b * Sq + sr) * QKS + 512 + h * 64 + scc;
    const bf16* gV = vt + (size_t)(bh * 64 + sr) * 512 + scc;
    uint4 rK = *(const uint4*)gK;                 // tile 0 in flight
    uint4 rV = *(const uint4*)gV;

    for (int kt = 0; kt < nk; ++kt) {
        const int buf = kt & 1;
        const int kv0 = kt * 64;
        uint4 nK, nV;
        if (kt + 1 < nk) {                        // issue next tile FIRST (stays in flight
            nK = *(const uint4*)(gK + (size_t)(kt + 1) * 64 * QKS);   //  across the barrier)
            nV = *(const uint4*)(gV + (size_t)(kt + 1) * 64);
        }
        *(uint4*)&lK[buf][sr][scc] = rK;          // compiler waits vmcnt for rK/rV only
        *(uint4*)&lV[buf][sr][scc] = rV;
        asm volatile("s_waitcnt lgkmcnt(0)" ::: "memory");
        __builtin_amdgcn_s_barrier();
        __builtin_amdgcn_sched_barrier(0);

        if (kv0 <= rowb + 15) {                   // wave-uniform: skip fully-masked tiles
            f32x4 sc[4];
            #pragma unroll
            for (int j = 0; j < 4; j++) sc[j] = z4();
            #pragma unroll
            for (int j = 0; j < 4; j++)
                #pragma unroll
                for (int ks = 0; ks < 2; ks++) {
                    short8 kf = *(const short8*)&lK[buf][j * 16 + l15][ks * 32 + l4 * 8];
                    sc[j] = __builtin_amdgcn_mfma_f32_16x16x32_bf16(qf[ks], kf, sc[j], 0, 0, 0);
                }
            if (kv0 + 63 > rowb) {                // some lane-row may violate causality
                #pragma unroll
                for (int j = 0; j < 4; j++)
                    #pragma unroll
                    for (int r = 0; r < 4; r++)
                        if (kv0 + j * 16 + l15 > rowb + l4 * 4 + r) sc[j][r] = -1e30f;
            }
            float corr[4];
            #pragma unroll
            for (int r = 0; r < 4; r++) {
                float m_ = fmaxf(fmaxf(sc[0][r], sc[1][r]), fmaxf(sc[2][r], sc[3][r]));
                #pragma unroll
                for (int d = 1; d < 16; d <<= 1) m_ = fmaxf(m_, __shfl_xor(m_, d, 64));
                float mo = mrow[r];
                float mn = fmaxf(mo, m_);
                mrow[r] = mn;
                corr[r] = __expf(mo - mn);
            }
            float p[4][4];
            #pragma unroll
            for (int j = 0; j < 4; j++)
                #pragma unroll
                for (int r = 0; r < 4; r++)
                    p[j][r] = __expf(sc[j][r] - mrow[r]);
            #pragma unroll
            for (int r = 0; r < 4; r++)
                ssum[r] = ssum[r] * corr[r] + p[0][r] + p[1][r] + p[2][r] + p[3][r];
            #pragma unroll
            for (int j = 0; j < 4; j++)
                #pragma unroll
                for (int r = 0; r < 4; r++)
                    lP[w][l4 * 4 + r][j * 16 + l15] = f2b(p[j][r]);
            #pragma unroll
            for (int j = 0; j < 4; j++) {
                o[j][0] *= corr[0]; o[j][1] *= corr[1]; o[j][2] *= corr[2]; o[j][3] *= corr[3];
            }
            #pragma unroll
            for (int ks = 0; ks < 2; ks++) {
                short8 pa = *(const short8*)&lP[w][l15][ks * 32 + l4 * 8];
                #pragma unroll
                for (int j = 0; j < 4; j++) {
                    short8 vb = *(const short8*)&lV[buf][j * 16 + l15][ks * 32 + l4 * 8];
                    o[j] = __builtin_amdgcn_mfma_f32_16x16x32_bf16(pa, vb, o[j], 0, 0, 0);
                }
            }
        }
        rK = nK; rV = nV;
    }
    #pragma unroll
    for (int r = 0; r < 4; r++) {
        float s = ssum[r];
        #pragma unroll
        for (int d = 1; d < 16; d <<= 1) s += __shfl_xor(s, d, 64);
        ssum[r] = 1.f / s;
    }
    #pragma unroll
    for (int j = 0; j < 4; j++)
        #pragma unroll
        for (int r = 0; r < 4; r++)
            av[(size_t)(b * Sq + rowb + l4 * 4 + r) * 512 + h * 64 + j * 16 + l15] = f2b(o[j][r] * ssum[r]);
}

extern "C" void kernel_launch(void* const* d_in, const int* in_sizes, int n_in,
                              void* d_out, int out_size, void* d_ws, size_t ws_size,
                              hipStream_t stream) {
    const int*   data = (const int*)d_in[0];
    const float* emb  = (const float*)d_in[1];
    const float* pos  = (const float*)d_in[2];
    const float* Wq   = (const float*)d_in[3];
    const float* Wkv  = (const float*)d_in[4];
    const float* Wo   = (const float*)d_in[5];
    const float* W1   = (const float*)d_in[6];
    const float* b1   = (const float*)d_in[7];
    const float* W2   = (const float*)d_in[8];
    const float* b2   = (const float*)d_in[9];
    const float* ln1g = (const float*)d_in[10];
    const float* ln1b = (const float*)d_in[11];
    const float* ln2g = (const float*)d_in[12];
    const float* ln2b = (const float*)d_in[13];
    const float* outb = (const float*)d_in[14];
    float* out = (float*)d_out;
    char* ws = (char*)d_ws;

    // enable 72KB dynamic LDS for the wide GEMM instantiations (idempotent, capture-safe)
    const int WLDS = 3 * (256 * 32 + 128 * 32) * 2;   // 73728
    (void)hipFuncSetAttribute((const void*)&k_gemmW<1>, hipFuncAttributeMaxDynamicSharedMemorySize, WLDS);
    (void)hipFuncSetAttribute((const void*)&k_gemmW<2>, hipFuncAttributeMaxDynamicSharedMemorySize, WLDS);
    (void)hipFuncSetAttribute((const void*)&k_gemmW<3>, hipFuncAttributeMaxDynamicSharedMemorySize, WLDS);
    (void)hipFuncSetAttribute((const void*)&k_gemmW<4>, hipFuncAttributeMaxDynamicSharedMemorySize, WLDS);

    size_t off = 0;
    auto take = [&](size_t bytes) { size_t r = off; off += (bytes + 255) & ~(size_t)255; return r; };
    float* hf    = (float*)(ws + take((size_t)Mtok * Dm * 4));
    bf16*  hb    = (bf16*)(ws + take((size_t)Mtok * Dm * 2));
    bf16*  qkvbf = (bf16*)(ws + take((size_t)Mtok * QKS * 2));
    bf16*  vtb   = (bf16*)(ws + take((size_t)Mtok * Dm * 2));
    bf16*  avb   = (bf16*)(ws + take((size_t)Mtok * Dm * 2));
    bf16*  part  = (bf16*)(ws + take((size_t)2 * Mtok * Dm * 2));   // 2 split-K partial slabs
    bf16*  ff1   = (bf16*)(ws + take((size_t)Mtok * DFFd * 2));
    float* cosT  = (float*)(ws + take((size_t)Sq * 32 * 4));
    float* sinT  = (float*)(ws + take((size_t)Sq * 32 * 4));
    bf16*  embT  = (bf16*)(ws + take((size_t)VPAD * Dm * 2));
    int*   cntb  = (int*)(ws + take((size_t)NCNT * 4));

    const size_t ofsQKV = 0;                                   // [1536][512]
    const size_t ofsO   = ofsQKV + (size_t)1536 * 512;
    const size_t ofsW1  = ofsO + (size_t)512 * 512;
    const size_t ofsW2  = ofsW1 + (size_t)512 * 2048;
    const size_t SLABE  = ofsW2 + (size_t)2048 * 512;          // 3,145,728 elems

    bf16* wT = (bf16*)(ws + off);
    size_t remain = (ws_size > off) ? (ws_size - off) : 0;
    bool upfront = remain >= SLABE * 12 * 2;

    k_sincos<<<(Sq * 32) / 256, 256, 0, stream>>>(cosT, sinT, cntb);
    k_embconv<<<(VPAD * Dm) / 256, 256, 0, stream>>>(emb, embT);
    k_embed<<<Mtok, 256, 0, stream>>>(data, emb, pos, hf, hb);

    if (upfront) {
        k_wtrans<<<dim3(16, 16, 12), 256, 0, stream>>>(Wq,  wT + ofsQKV,             512, 512,  (long long)512 * 512,  (long long)SLABE);
        k_wtrans<<<dim3(32, 16, 12), 256, 0, stream>>>(Wkv, wT + ofsQKV + 512 * 512, 512, 1024, (long long)512 * 1024, (long long)SLABE);
        k_wtrans<<<dim3(16, 16, 12), 256, 0, stream>>>(Wo,  wT + ofsO,  512, 512,  (long long)512 * 512,  (long long)SLABE);
        k_wtrans<<<dim3(64, 16, 12), 256, 0, stream>>>(W1,  wT + ofsW1, 512, 2048, (long long)512 * 2048, (long long)SLABE);
        k_wtrans<<<dim3(16, 64, 12), 256, 0, stream>>>(W2,  wT + ofsW2, 2048, 512, (long long)2048 * 512, (long long)SLABE);
    }

    for (int l = 0; l < Lw; l++) {
        bf16* slab = wT + (upfront ? (size_t)l * SLABE : 0);
        if (!upfront) {
            k_wtrans<<<dim3(16, 16, 1), 256, 0, stream>>>(Wq  + (size_t)l * 512 * 512,  slab + ofsQKV,             512, 512,  0, 0);
            k_wtrans<<<dim3(32, 16, 1), 256, 0, stream>>>(Wkv + (size_t)l * 512 * 1024, slab + ofsQKV + 512 * 512, 512, 1024, 0, 0);
            k_wtrans<<<dim3(16, 16, 1), 256, 0, stream>>>(Wo  + (size_t)l * 512 * 512,  slab + ofsO,  512, 512,  0, 0);
            k_wtrans<<<dim3(64, 16, 1), 256, 0, stream>>>(W1  + (size_t)l * 512 * 2048, slab + ofsW1, 512, 2048, 0, 0);
            k_wtrans<<<dim3(16, 64, 1), 256, 0, stream>>>(W2  + (size_t)l * 2048 * 512, slab + ofsW2, 2048, 512, 0, 0);
        }
        // fused qkv projection: RoPE'd q|k -> qkvbf[M][1024], v -> vtb transposed
        k_gemmW<4><<<dim3(12, 32, 1), 512, WLDS, stream>>>(hb, slab + ofsQKV, qkvbf, vtb, nullptr, cosT, sinT,
                                                           Mtok, 1536, 512, 512, 512,
                                                           nullptr, nullptr, nullptr, nullptr, nullptr);
        // attention (QBLK=128, 8 waves, double-buffered KV)
        k_attn<<<dim3(4, 128), 512, 0, stream>>>(qkvbf, vtb, avb);
        // out proj (split-K=2, 256 blocks co-resident) + FUSED add&LN1
        k_gemmW<1><<<dim3(4, 32, 2), 512, WLDS, stream>>>(avb, slab + ofsO, part, nullptr, nullptr, nullptr, nullptr,
                                                          Mtok, 512, 256, 512, 512,
                                                          hf, hb, ln1g + (size_t)l * Dm, ln1b + (size_t)l * Dm,
                                                          cntb + (size_t)(l * 2) * 32);
        // FFN
        k_gemmW<2><<<dim3(16, 32, 1), 512, WLDS, stream>>>(hb, slab + ofsW1, ff1, nullptr, b1 + (size_t)l * DFFd,
                                                           nullptr, nullptr, Mtok, 2048, 512, 512, 512,
                                                           nullptr, nullptr, nullptr, nullptr, nullptr);
        // ffn2 (split-K=2, 256 blocks co-resident) + FUSED add&LN2 (+b2)
        k_gemmW<1><<<dim3(4, 32, 2), 512, WLDS, stream>>>(ff1, slab + ofsW2, part, nullptr, b2 + (size_t)l * Dm,
                                                          nullptr, nullptr, Mtok, 512, 1024, 2048, 2048,
                                                          hf, hb, ln2g + (size_t)l * Dm, ln2b + (size_t)l * Dm,
                                                          cntb + (size_t)(l * 2 + 1) * 32);
    }
    // final vocab projection -> d_out (f32, col-guarded, wide kernel)
    k_gemmW<3><<<dim3(5, 32, 1), 512, WLDS, stream>>>(hb, embT, out, nullptr, outb, nullptr, nullptr,
                                                      Mtok, VPAD, 512, 512, 512,
                                                      nullptr, nullptr, nullptr, nullptr, nullptr);
}

// Round 5
// 1618.848 us; speedup vs baseline: 1.3547x; 1.3547x over previous
//
#include <hip/hip_runtime.h>
#include <hip/hip_bf16.h>

typedef __hip_bfloat16 bf16;
typedef __attribute__((ext_vector_type(8))) short short8;
typedef __attribute__((ext_vector_type(4))) float f32x4;

static constexpr int Bz = 16, Sq = 512, Lw = 12, Dm = 512, Hh = 8, DFFd = 2048, Vv = 631;
static constexpr int Mtok = Bz * Sq;   // 8192
static constexpr int VPAD = 640;       // 631 padded to /128
static constexpr int QKS = 1024;       // qkv buffer row stride (q 0-511, k 512-1023; v -> vt)

__device__ __forceinline__ bf16 f2b(float x) { return __float2bfloat16(x); }
__device__ __forceinline__ float bfu(unsigned short s) {
    union { unsigned u; float f; } c; c.u = (unsigned)s << 16; return c.f;
}

__device__ __forceinline__ f32x4 z4() { f32x4 v; v[0]=0.f; v[1]=0.f; v[2]=0.f; v[3]=0.f; return v; }

__device__ __forceinline__ void gload_lds16(const bf16* g, bf16* l) {
    __builtin_amdgcn_global_load_lds(
        (const __attribute__((address_space(1))) unsigned int*)(g),
        (__attribute__((address_space(3))) unsigned int*)(l),
        16, 0, 0);
}

// ---------------- sin/cos tables: [S][32] (per even/odd pair) ----------------
__global__ void k_sincos(float* __restrict__ cosT, float* __restrict__ sinT) {
    int i = blockIdx.x * 256 + threadIdx.x;            // S*32 = 16384
    int s = i >> 5, f = i & 31;
    float inv = powf(10000.0f, -(float)(2 * f) / 64.0f);
    float t = (float)s * inv;
    sinT[i] = sinf(t);
    cosT[i] = cosf(t);
}

// ---------------- emb -> bf16 padded [VPAD][512] (B^T for final GEMM) ----------------
__global__ void k_embconv(const float* __restrict__ emb, bf16* __restrict__ embT) {
    int i = blockIdx.x * 256 + threadIdx.x;            // VPAD*512
    int n = i >> 9;
    embT[i] = (n < Vv) ? f2b(emb[i]) : f2b(0.0f);
}

// ---------------- h = emb[data] + pos ----------------
__global__ void k_embed(const int* __restrict__ data, const float* __restrict__ emb,
                        const float* __restrict__ pos, float* __restrict__ hf, bf16* __restrict__ hb) {
    int tok = blockIdx.x;
    int id = data[tok];
    int s = tok & (Sq - 1);
    for (int d = threadIdx.x; d < Dm; d += 256) {
        float v = emb[id * Dm + d] + pos[s * Dm + d];
        hf[(size_t)tok * Dm + d] = v;
        hb[(size_t)tok * Dm + d] = f2b(v);
    }
}

// ---------------- weight transpose+convert: src f32 [K][N] -> dst bf16 [N][K] ----------------
__global__ void k_wtrans(const float* __restrict__ src, bf16* __restrict__ dst,
                         int K, int N, long long sStride, long long dStride) {
    src += (long long)blockIdx.z * sStride;
    dst += (long long)blockIdx.z * dStride;
    __shared__ float tile[32][33];
    int k0 = blockIdx.y * 32, n0 = blockIdx.x * 32;
    int tx = threadIdx.x & 31, ty = threadIdx.x >> 5;  // ty 0..7
    #pragma unroll
    for (int r = ty; r < 32; r += 8) tile[r][tx] = src[(size_t)(k0 + r) * N + n0 + tx];
    __syncthreads();
    #pragma unroll
    for (int r = ty; r < 32; r += 8) dst[(size_t)(n0 + r) * K + k0 + tx] = f2b(tile[tx][r]);
}

// ================= WIDE GEMM: BM x 128 tile (BM=256 or 128), BK=32, 8 waves, 3-ring ====
// BM=256: 72KB LDS -> 2 blocks/CU, 3 loads/stage, vmcnt(3).
// BM=128: 48KB LDS -> 3 blocks/CU, 2 loads/stage, vmcnt(2). Used for under-filled
//         launches (qkv 768=3/CU, oproj+ffn2 512=2/CU, vocab 320) per the fill model:
//         1 block/CU has no inter-block overlap partner (m114 mechanism).
// Counted vmcnt per iter (tile kt landed, kt+1 in flight ACROSS the raw s_barrier).
// STAGE(kt+2) post-barrier overwrites buf[kt-1] whose reads retired pre-barrier.
// 64B-row swizzle: chunk XOR (row>>1)&3 (2-way max = free). XCD swizzle. z = split-K.
// EPI: 1 = bf16 partial (z=0 -> Cout, z=1 -> Cout2); 2 = +bias,relu,bf16;
//      3 = +bias, f32 out [M][Vv] col-guarded (vocab);
//      4 = qkv: RoPE'd q(x0.125)|k -> Cout[M][1024], v-cols -> vt (Cout2) transposed
template<int EPI, int BM>
__global__ __launch_bounds__(512) void k_gemmW(const bf16* __restrict__ A, const bf16* __restrict__ Bt,
                                               void* __restrict__ Cout, void* __restrict__ Cout2,
                                               const float* __restrict__ bias,
                                               const float* __restrict__ cosT, const float* __restrict__ sinT,
                                               int M, int N, int K, int ldA, int ldB) {
    constexpr int PA  = BM / 128;   // A 16B-chunks per thread per stage
    constexpr int NI  = BM / 64;    // i-frags per wave
    constexpr int WRS = BM / 4;     // wave row span
    extern __shared__ __align__(16) char smem[];
    bf16* lAbase = (bf16*)smem;                        // 3 x BM*32
    bf16* lBbase = (bf16*)(smem + 3 * BM * 32 * 2);    // 3 x 128*32

    const int t = threadIdx.x;                 // 0..511
    const int lane = t & 63;
    const int wave = t >> 6;                   // 0..7
    const int wr = wave >> 1, wc = wave & 1;   // 4 x 2 wave grid
    const int l15 = lane & 15, l4 = lane >> 4;

    // XCD swizzle over linearized 3D grid (nwg % 8 == 0 for all launches here)
    const int gx = gridDim.x, gy = gridDim.y;
    const int nwg = gx * gy * gridDim.z;
    const int cpx = nwg >> 3;
    int lin = (blockIdx.z * gy + blockIdx.y) * gx + blockIdx.x;
    lin = (lin & 7) * cpx + (lin >> 3);
    const int bn = lin % gx;
    const int rem = lin / gx;
    const int bm = rem % gy;
    const int bz = rem / gy;

    const bf16* Ab = A + (size_t)(bm * BM) * ldA + (size_t)bz * K;
    const bf16* Bb = Bt + (size_t)(bn * 128) * ldB + (size_t)bz * K;

    // staging maps: 16B chunk q -> row r = q>>2, phys slot s = q&3 holds logical s^((r>>1)&3)
    int soffA[PA], soffB0;
    #pragma unroll
    for (int p = 0; p < PA; p++) {
        int q = p * 512 + t, r = q >> 2, s = q & 3;
        soffA[p] = r * ldA + ((s ^ ((r >> 1) & 3)) << 3);
    }
    {
        int r = t >> 2, s = t & 3;
        soffB0 = r * ldB + ((s ^ ((r >> 1) & 3)) << 3);
    }

    f32x4 acc[NI][4];
    #pragma unroll
    for (int i = 0; i < NI; i++)
        #pragma unroll
        for (int j = 0; j < 4; j++) acc[i][j] = z4();

    auto STAGE = [&](int buf, int kt) {         // PA+1 gload_lds per thread
        const int k0 = kt << 5;
        bf16* la = lAbase + buf * (BM * 32);
        bf16* lb = lBbase + buf * (128 * 32);
        #pragma unroll
        for (int p = 0; p < PA; p++)
            gload_lds16(Ab + (size_t)soffA[p] + k0, &la[(p * 512 + t) * 8]);
        gload_lds16(Bb + (size_t)soffB0 + k0, &lb[t * 8]);
    };

    auto COMPUTE = [&](int buf) {               // one BK=32 slice: NI*4 MFMA/wave
        const char* la = (const char*)(lAbase + buf * (BM * 32));
        const char* lb = (const char*)(lBbase + buf * (128 * 32));
        short8 af[NI], bfr[4];
        #pragma unroll
        for (int i = 0; i < NI; i++) {
            int row = wr * WRS + i * 16 + l15;
            af[i] = *(const short8*)(la + row * 64 + (((l4 ^ (row >> 1)) & 3) << 4));
        }
        #pragma unroll
        for (int j = 0; j < 4; j++) {
            int row = wc * 64 + j * 16 + l15;
            bfr[j] = *(const short8*)(lb + row * 64 + (((l4 ^ (row >> 1)) & 3) << 4));
        }
        #pragma unroll
        for (int i = 0; i < NI; i++)
            #pragma unroll
            for (int j = 0; j < 4; j++)
                acc[i][j] = __builtin_amdgcn_mfma_f32_16x16x32_bf16(af[i], bfr[j], acc[i][j], 0, 0, 0);
    };

    const int nk = K >> 5;
    STAGE(0, 0);
    STAGE(1, 1);
    int kt = 0;
    for (; kt < nk - 1; ++kt) {
        // tile kt landed; kt+1's (PA+1) loads still in flight across the barrier
        if constexpr (PA == 2) asm volatile("s_waitcnt vmcnt(3)" ::: "memory");
        else                   asm volatile("s_waitcnt vmcnt(2)" ::: "memory");
        __builtin_amdgcn_s_barrier();
        if (kt + 2 < nk) STAGE((kt + 2) % 3, kt + 2);
        __builtin_amdgcn_s_setprio(1);
        COMPUTE(kt % 3);
        __builtin_amdgcn_s_setprio(0);
    }
    asm volatile("s_waitcnt vmcnt(0)" ::: "memory");
    __builtin_amdgcn_s_barrier();
    __builtin_amdgcn_s_setprio(1);
    COMPUTE(kt % 3);
    __builtin_amdgcn_s_setprio(0);

    // ---- epilogue ----
    #pragma unroll
    for (int i = 0; i < NI; i++) {
        #pragma unroll
        for (int j = 0; j < 4; j++) {
            const int col = bn * 128 + wc * 64 + j * 16 + l15;
            const int row0 = bm * BM + wr * WRS + i * 16 + l4 * 4;
            if (EPI == 4 && col >= 1024) {
                // v columns -> vt[bh][d][s], 4 consecutive s packed as 8B
                int h = (col - 1024) >> 6, d = (col - 1024) & 63;
                int b = row0 >> 9, s0 = row0 & 511;
                bf16 pk[4];
                #pragma unroll
                for (int r = 0; r < 4; r++) pk[r] = f2b(acc[i][j][r]);
                *(ushort4*)&((bf16*)Cout2)[((size_t)(b * 8 + h) * 64 + d) * 512 + s0] =
                    *(const ushort4*)pk;
                continue;
            }
            #pragma unroll
            for (int r = 0; r < 4; r++) {
                int row = row0 + r;
                float v = acc[i][j][r];
                if (EPI == 1) {
                    bf16* Co = (bf16*)(bz ? Cout2 : Cout);
                    Co[(size_t)row * N + col] = f2b(v);
                } else if (EPI == 2) {
                    v += bias[col];
                    v = v > 0.f ? v : 0.f;
                    ((bf16*)Cout)[(size_t)row * N + col] = f2b(v);
                } else if (EPI == 3) {
                    if (col < Vv) ((float*)Cout)[(size_t)row * Vv + col] = v + bias[col];
                } else {
                    // EPI 4, col < 1024: RoPE on q (scaled 1/8) and k
                    float p = __shfl_xor(v, 1, 64);   // partner column col^1, same row
                    int srow = row & (Sq - 1);
                    int f = (col >> 1) & 31;
                    float cc = cosT[srow * 32 + f], sn = sinT[srow * 32 + f];
                    float o = (col & 1) ? (v * cc + p * sn) : (v * cc - p * sn);
                    if (col < 512) o *= 0.125f;
                    ((bf16*)Cout)[(size_t)row * QKS + col] = f2b(o);
                }
            }
        }
    }
}

// ---------------- causal flash attention: 8 waves x 16 q-rows (QBLK=128), KV tiles of 64 ----
// double-buffered K/V LDS (one raw s_barrier per tile, vmcnt NOT drained -> next tile's
// global loads stay in flight under compute); lP padded to 88; waves skip fully-masked tiles.
__global__ __launch_bounds__(512) void k_attn(const bf16* __restrict__ qkv,
                                              const bf16* __restrict__ vt, bf16* __restrict__ av) {
    __shared__ __align__(16) bf16 lK[2][64][80];
    __shared__ __align__(16) bf16 lV[2][64][80];
    __shared__ __align__(16) bf16 lP[8][16][88];
    const int tq = blockIdx.x, bh = blockIdx.y;
    const int b = bh >> 3, h = bh & 7;
    const int t = threadIdx.x, lane = t & 63, w = t >> 6;   // w 0..7
    const int l15 = lane & 15, l4 = lane >> 4;
    const int q0 = tq * 128;
    const int rowb = q0 + w * 16;                 // wave's first q-row

    short8 qf[2];
    {
        const bf16* qr = qkv + (size_t)(b * Sq + rowb + l15) * QKS + h * 64 + l4 * 8;
        qf[0] = *(const short8*)qr;
        qf[1] = *(const short8*)(qr + 32);
    }
    f32x4 o[4];
    #pragma unroll
    for (int j = 0; j < 4; j++) o[j] = z4();
    float mrow[4] = {-1e30f, -1e30f, -1e30f, -1e30f};
    float ssum[4] = {0.f, 0.f, 0.f, 0.f};

    const int nk = (q0 >> 6) + 2;                 // KV tiles covering rows [q0, q0+128)
    const int sr = t >> 3, scc = (t & 7) * 8;     // 512 threads x 16B = full 64x64 tile
    const bf16* gK = qkv + (size_t)(b * Sq + sr) * QKS + 512 + h * 64 + scc;
    const bf16* gV = vt + (size_t)(bh * 64 + sr) * 512 + scc;
    uint4 rK = *(const uint4*)gK;                 // tile 0 in flight
    uint4 rV = *(const uint4*)gV;

    for (int kt = 0; kt < nk; ++kt) {
        const int buf = kt & 1;
        const int kv0 = kt * 64;
        uint4 nK, nV;
        if (kt + 1 < nk) {                        // issue next tile FIRST (stays in flight
            nK = *(const uint4*)(gK + (size_t)(kt + 1) * 64 * QKS);   //  across the barrier)
            nV = *(const uint4*)(gV + (size_t)(kt + 1) * 64);
        }
        *(uint4*)&lK[buf][sr][scc] = rK;          // compiler waits vmcnt for rK/rV only
        *(uint4*)&lV[buf][sr][scc] = rV;
        asm volatile("s_waitcnt lgkmcnt(0)" ::: "memory");
        __builtin_amdgcn_s_barrier();
        __builtin_amdgcn_sched_barrier(0);

        if (kv0 <= rowb + 15) {                   // wave-uniform: skip fully-masked tiles
            f32x4 sc[4];
            #pragma unroll
            for (int j = 0; j < 4; j++) sc[j] = z4();
            #pragma unroll
            for (int j = 0; j < 4; j++)
                #pragma unroll
                for (int ks = 0; ks < 2; ks++) {
                    short8 kf = *(const short8*)&lK[buf][j * 16 + l15][ks * 32 + l4 * 8];
                    sc[j] = __builtin_amdgcn_mfma_f32_16x16x32_bf16(qf[ks], kf, sc[j], 0, 0, 0);
                }
            if (kv0 + 63 > rowb) {                // some lane-row may violate causality
                #pragma unroll
                for (int j = 0; j < 4; j++)
                    #pragma unroll
                    for (int r = 0; r < 4; r++)
                        if (kv0 + j * 16 + l15 > rowb + l4 * 4 + r) sc[j][r] = -1e30f;
            }
            float corr[4];
            #pragma unroll
            for (int r = 0; r < 4; r++) {
                float m_ = fmaxf(fmaxf(sc[0][r], sc[1][r]), fmaxf(sc[2][r], sc[3][r]));
                #pragma unroll
                for (int d = 1; d < 16; d <<= 1) m_ = fmaxf(m_, __shfl_xor(m_, d, 64));
                float mo = mrow[r];
                float mn = fmaxf(mo, m_);
                mrow[r] = mn;
                corr[r] = __expf(mo - mn);
            }
            float p[4][4];
            #pragma unroll
            for (int j = 0; j < 4; j++)
                #pragma unroll
                for (int r = 0; r < 4; r++)
                    p[j][r] = __expf(sc[j][r] - mrow[r]);
            #pragma unroll
            for (int r = 0; r < 4; r++)
                ssum[r] = ssum[r] * corr[r] + p[0][r] + p[1][r] + p[2][r] + p[3][r];
            #pragma unroll
            for (int j = 0; j < 4; j++)
                #pragma unroll
                for (int r = 0; r < 4; r++)
                    lP[w][l4 * 4 + r][j * 16 + l15] = f2b(p[j][r]);
            #pragma unroll
            for (int j = 0; j < 4; j++) {
                o[j][0] *= corr[0]; o[j][1] *= corr[1]; o[j][2] *= corr[2]; o[j][3] *= corr[3];
            }
            #pragma unroll
            for (int ks = 0; ks < 2; ks++) {
                short8 pa = *(const short8*)&lP[w][l15][ks * 32 + l4 * 8];
                #pragma unroll
                for (int j = 0; j < 4; j++) {
                    short8 vb = *(const short8*)&lV[buf][j * 16 + l15][ks * 32 + l4 * 8];
                    o[j] = __builtin_amdgcn_mfma_f32_16x16x32_bf16(pa, vb, o[j], 0, 0, 0);
                }
            }
        }
        rK = nK; rV = nV;
    }
    #pragma unroll
    for (int r = 0; r < 4; r++) {
        float s = ssum[r];
        #pragma unroll
        for (int d = 1; d < 16; d <<= 1) s += __shfl_xor(s, d, 64);
        ssum[r] = 1.f / s;
    }
    #pragma unroll
    for (int j = 0; j < 4; j++)
        #pragma unroll
        for (int r = 0; r < 4; r++)
            av[(size_t)(b * Sq + rowb + l4 * 4 + r) * 512 + h * 64 + j * 16 + l15] = f2b(o[j][r] * ssum[r]);
}

// -------- h = LN(h + d1 + d2 [+ bias]): wave-per-row, no LDS/barriers ----
template<bool ADDB>
__global__ __launch_bounds__(256) void k_addln(float* __restrict__ hf, bf16* __restrict__ hb,
                                               const bf16* __restrict__ d1, const bf16* __restrict__ d2,
                                               const float* __restrict__ bias,
                                               const float* __restrict__ gamma, const float* __restrict__ beta) {
    const int lane = threadIdx.x & 63, w = threadIdx.x >> 6;
    const int row = blockIdx.x * 4 + w;
    const size_t base = (size_t)row * Dm + lane * 8;
    float v[8];
    float4 h0 = *(const float4*)&hf[base];
    float4 h1 = *(const float4*)&hf[base + 4];
    short8 a8 = *(const short8*)&d1[base];
    short8 b8 = *(const short8*)&d2[base];
    v[0] = h0.x; v[1] = h0.y; v[2] = h0.z; v[3] = h0.w;
    v[4] = h1.x; v[5] = h1.y; v[6] = h1.z; v[7] = h1.w;
    #pragma unroll
    for (int k = 0; k < 8; k++)
        v[k] += bfu((unsigned short)a8[k]) + bfu((unsigned short)b8[k]);
    if (ADDB) {
        float4 bb0 = *(const float4*)&bias[lane * 8];
        float4 bb1 = *(const float4*)&bias[lane * 8 + 4];
        v[0] += bb0.x; v[1] += bb0.y; v[2] += bb0.z; v[3] += bb0.w;
        v[4] += bb1.x; v[5] += bb1.y; v[6] += bb1.z; v[7] += bb1.w;
    }
    float s = 0.f, sq = 0.f;
    #pragma unroll
    for (int k = 0; k < 8; k++) { s += v[k]; sq += v[k] * v[k]; }
    #pragma unroll
    for (int m = 1; m < 64; m <<= 1) { s += __shfl_xor(s, m, 64); sq += __shfl_xor(sq, m, 64); }
    float mean = s * (1.f / Dm);
    float var = sq * (1.f / Dm) - mean * mean;
    float inv = rsqrtf(var + 1e-5f);
    float4 g0 = *(const float4*)&gamma[lane * 8];
    float4 g1 = *(const float4*)&gamma[lane * 8 + 4];
    float4 e0 = *(const float4*)&beta[lane * 8];
    float4 e1 = *(const float4*)&beta[lane * 8 + 4];
    float gs[8] = {g0.x, g0.y, g0.z, g0.w, g1.x, g1.y, g1.z, g1.w};
    float es[8] = {e0.x, e0.y, e0.z, e0.w, e1.x, e1.y, e1.z, e1.w};
    float ov[8];
    short8 ob;
    #pragma unroll
    for (int k = 0; k < 8; k++) {
        ov[k] = (v[k] - mean) * inv * gs[k] + es[k];
        ob[k] = (short)__bfloat16_as_ushort(f2b(ov[k]));
    }
    float4 o0; o0.x = ov[0]; o0.y = ov[1]; o0.z = ov[2]; o0.w = ov[3];
    float4 o1; o1.x = ov[4]; o1.y = ov[5]; o1.z = ov[6]; o1.w = ov[7];
    *(float4*)&hf[base] = o0;
    *(float4*)&hf[base + 4] = o1;
    *(short8*)&hb[base] = ob;
}

extern "C" void kernel_launch(void* const* d_in, const int* in_sizes, int n_in,
                              void* d_out, int out_size, void* d_ws, size_t ws_size,
                              hipStream_t stream) {
    const int*   data = (const int*)d_in[0];
    const float* emb  = (const float*)d_in[1];
    const float* pos  = (const float*)d_in[2];
    const float* Wq   = (const float*)d_in[3];
    const float* Wkv  = (const float*)d_in[4];
    const float* Wo   = (const float*)d_in[5];
    const float* W1   = (const float*)d_in[6];
    const float* b1   = (const float*)d_in[7];
    const float* W2   = (const float*)d_in[8];
    const float* b2   = (const float*)d_in[9];
    const float* ln1g = (const float*)d_in[10];
    const float* ln1b = (const float*)d_in[11];
    const float* ln2g = (const float*)d_in[12];
    const float* ln2b = (const float*)d_in[13];
    const float* outb = (const float*)d_in[14];
    float* out = (float*)d_out;
    char* ws = (char*)d_ws;

    // dynamic LDS per tile size (idempotent, capture-safe)
    const int WL256 = 3 * (256 * 32 + 128 * 32) * 2;   // 73728
    const int WL128 = 3 * (128 * 32 + 128 * 32) * 2;   // 49152
    (void)hipFuncSetAttribute((const void*)&k_gemmW<1, 128>, hipFuncAttributeMaxDynamicSharedMemorySize, WL128);
    (void)hipFuncSetAttribute((const void*)&k_gemmW<2, 256>, hipFuncAttributeMaxDynamicSharedMemorySize, WL256);
    (void)hipFuncSetAttribute((const void*)&k_gemmW<3, 128>, hipFuncAttributeMaxDynamicSharedMemorySize, WL128);
    (void)hipFuncSetAttribute((const void*)&k_gemmW<4, 128>, hipFuncAttributeMaxDynamicSharedMemorySize, WL128);

    size_t off = 0;
    auto take = [&](size_t bytes) { size_t r = off; off += (bytes + 255) & ~(size_t)255; return r; };
    float* hf    = (float*)(ws + take((size_t)Mtok * Dm * 4));
    bf16*  hb    = (bf16*)(ws + take((size_t)Mtok * Dm * 2));
    bf16*  qkvbf = (bf16*)(ws + take((size_t)Mtok * QKS * 2));
    bf16*  vtb   = (bf16*)(ws + take((size_t)Mtok * Dm * 2));
    bf16*  avb   = (bf16*)(ws + take((size_t)Mtok * Dm * 2));
    bf16*  tmpb  = (bf16*)(ws + take((size_t)Mtok * Dm * 2));
    bf16*  tmp2b = (bf16*)(ws + take((size_t)Mtok * Dm * 2));
    bf16*  ff1   = (bf16*)(ws + take((size_t)Mtok * DFFd * 2));
    float* cosT  = (float*)(ws + take((size_t)Sq * 32 * 4));
    float* sinT  = (float*)(ws + take((size_t)Sq * 32 * 4));
    bf16*  embT  = (bf16*)(ws + take((size_t)VPAD * Dm * 2));

    const size_t ofsQKV = 0;                                   // [1536][512]
    const size_t ofsO   = ofsQKV + (size_t)1536 * 512;
    const size_t ofsW1  = ofsO + (size_t)512 * 512;
    const size_t ofsW2  = ofsW1 + (size_t)512 * 2048;
    const size_t SLABE  = ofsW2 + (size_t)2048 * 512;          // 3,145,728 elems

    bf16* wT = (bf16*)(ws + off);
    size_t remain = (ws_size > off) ? (ws_size - off) : 0;
    bool upfront = remain >= SLABE * 12 * 2;

    k_sincos<<<(Sq * 32) / 256, 256, 0, stream>>>(cosT, sinT);
    k_embconv<<<(VPAD * Dm) / 256, 256, 0, stream>>>(emb, embT);
    k_embed<<<Mtok, 256, 0, stream>>>(data, emb, pos, hf, hb);

    if (upfront) {
        k_wtrans<<<dim3(16, 16, 12), 256, 0, stream>>>(Wq,  wT + ofsQKV,             512, 512,  (long long)512 * 512,  (long long)SLABE);
        k_wtrans<<<dim3(32, 16, 12), 256, 0, stream>>>(Wkv, wT + ofsQKV + 512 * 512, 512, 1024, (long long)512 * 1024, (long long)SLABE);
        k_wtrans<<<dim3(16, 16, 12), 256, 0, stream>>>(Wo,  wT + ofsO,  512, 512,  (long long)512 * 512,  (long long)SLABE);
        k_wtrans<<<dim3(64, 16, 12), 256, 0, stream>>>(W1,  wT + ofsW1, 512, 2048, (long long)512 * 2048, (long long)SLABE);
        k_wtrans<<<dim3(16, 64, 12), 256, 0, stream>>>(W2,  wT + ofsW2, 2048, 512, (long long)2048 * 512, (long long)SLABE);
    }

    for (int l = 0; l < Lw; l++) {
        bf16* slab = wT + (upfront ? (size_t)l * SLABE : 0);
        if (!upfront) {
            k_wtrans<<<dim3(16, 16, 1), 256, 0, stream>>>(Wq  + (size_t)l * 512 * 512,  slab + ofsQKV,             512, 512,  0, 0);
            k_wtrans<<<dim3(32, 16, 1), 256, 0, stream>>>(Wkv + (size_t)l * 512 * 1024, slab + ofsQKV + 512 * 512, 512, 1024, 0, 0);
            k_wtrans<<<dim3(16, 16, 1), 256, 0, stream>>>(Wo  + (size_t)l * 512 * 512,  slab + ofsO,  512, 512,  0, 0);
            k_wtrans<<<dim3(64, 16, 1), 256, 0, stream>>>(W1  + (size_t)l * 512 * 2048, slab + ofsW1, 512, 2048, 0, 0);
            k_wtrans<<<dim3(16, 64, 1), 256, 0, stream>>>(W2  + (size_t)l * 2048 * 512, slab + ofsW2, 2048, 512, 0, 0);
        }
        // fused qkv projection: RoPE'd q|k -> qkvbf[M][1024], v -> vtb transposed
        // BM=128 -> 768 blocks = 3/CU exact
        k_gemmW<4, 128><<<dim3(12, 64, 1), 512, WL128, stream>>>(hb, slab + ofsQKV, qkvbf, vtb, nullptr, cosT, sinT,
                                                                 Mtok, 1536, 512, 512, 512);
        // attention (QBLK=128, 8 waves, double-buffered KV)
        k_attn<<<dim3(4, 128), 512, 0, stream>>>(qkvbf, vtb, avb);
        // out proj (bf16 partials, split-K=2; BM=128 -> 512 blocks = 2/CU) + add&LN1
        k_gemmW<1, 128><<<dim3(4, 64, 2), 512, WL128, stream>>>(avb, slab + ofsO, tmpb, tmp2b, nullptr, nullptr, nullptr,
                                                                Mtok, 512, 256, 512, 512);
        k_addln<false><<<Mtok / 4, 256, 0, stream>>>(hf, hb, tmpb, tmp2b, nullptr,
                                                     ln1g + (size_t)l * Dm, ln1b + (size_t)l * Dm);
        // FFN1 (BM=256 -> 512 blocks = 2/CU exact)
        k_gemmW<2, 256><<<dim3(16, 32, 1), 512, WL256, stream>>>(hb, slab + ofsW1, ff1, nullptr, b1 + (size_t)l * DFFd,
                                                                 nullptr, nullptr, Mtok, 2048, 512, 512, 512);
        // FFN2 (split-K=2; BM=128 -> 512 blocks = 2/CU)
        k_gemmW<1, 128><<<dim3(4, 64, 2), 512, WL128, stream>>>(ff1, slab + ofsW2, tmpb, tmp2b, nullptr, nullptr, nullptr,
                                                                Mtok, 512, 1024, 2048, 2048);
        k_addln<true><<<Mtok / 4, 256, 0, stream>>>(hf, hb, tmpb, tmp2b, b2 + (size_t)l * Dm,
                                                    ln2g + (size_t)l * Dm, ln2b + (size_t)l * Dm);
    }
    // final vocab projection -> d_out (f32, col-guarded; BM=128 -> 320 blocks)
    k_gemmW<3, 128><<<dim3(5, 64, 1), 512, WL128, stream>>>(hb, embT, out, nullptr, outb, nullptr, nullptr,
                                                            Mtok, VPAD, 512, 512, 512);
}

// Round 6
// 1509.911 us; speedup vs baseline: 1.4524x; 1.0721x over previous
//
#include <hip/hip_runtime.h>
#include <hip/hip_bf16.h>

typedef __hip_bfloat16 bf16;
typedef __attribute__((ext_vector_type(8))) short short8;
typedef __attribute__((ext_vector_type(4))) float f32x4;

static constexpr int Bz = 16, Sq = 512, Lw = 12, Dm = 512, Hh = 8, DFFd = 2048, Vv = 631;
static constexpr int Mtok = Bz * Sq;   // 8192
static constexpr int VPAD = 640;       // 631 padded to /128
static constexpr int QKS = 1024;       // qkv buffer row stride (q 0-511, k 512-1023; v -> vt)

__device__ __forceinline__ bf16 f2b(float x) { return __float2bfloat16(x); }
__device__ __forceinline__ float bfu(unsigned short s) {
    union { unsigned u; float f; } c; c.u = (unsigned)s << 16; return c.f;
}

__device__ __forceinline__ f32x4 z4() { f32x4 v; v[0]=0.f; v[1]=0.f; v[2]=0.f; v[3]=0.f; return v; }

__device__ __forceinline__ void gload_lds16(const bf16* g, bf16* l) {
    __builtin_amdgcn_global_load_lds(
        (const __attribute__((address_space(1))) unsigned int*)(g),
        (__attribute__((address_space(3))) unsigned int*)(l),
        16, 0, 0);
}

// ---------------- sin/cos tables: [S][32] (per even/odd pair) ----------------
__global__ void k_sincos(float* __restrict__ cosT, float* __restrict__ sinT) {
    int i = blockIdx.x * 256 + threadIdx.x;            // S*32 = 16384
    int s = i >> 5, f = i & 31;
    float inv = powf(10000.0f, -(float)(2 * f) / 64.0f);
    float t = (float)s * inv;
    sinT[i] = sinf(t);
    cosT[i] = cosf(t);
}

// ---------------- emb -> bf16 padded [VPAD][512] (B^T for final GEMM) ----------------
__global__ void k_embconv(const float* __restrict__ emb, bf16* __restrict__ embT) {
    int i = blockIdx.x * 256 + threadIdx.x;            // VPAD*512
    int n = i >> 9;
    embT[i] = (n < Vv) ? f2b(emb[i]) : f2b(0.0f);
}

// ---------------- h = emb[data] + pos (bf16 residual stream only) ----------------
// The model re-normalizes each sublayer (h = LN(h+delta)), so carrying h in bf16 only
// injects h's own bf16 rounding into the add — all GEMM consumers already read bf16 h.
__global__ void k_embed(const int* __restrict__ data, const float* __restrict__ emb,
                        const float* __restrict__ pos, bf16* __restrict__ hb) {
    int tok = blockIdx.x;
    int id = data[tok];
    int s = tok & (Sq - 1);
    for (int d = threadIdx.x; d < Dm; d += 256) {
        float v = emb[id * Dm + d] + pos[s * Dm + d];
        hb[(size_t)tok * Dm + d] = f2b(v);
    }
}

// ---------------- weight transpose+convert: src f32 [K][N] -> dst bf16 [N][K] ----------------
__global__ void k_wtrans(const float* __restrict__ src, bf16* __restrict__ dst,
                         int K, int N, long long sStride, long long dStride) {
    src += (long long)blockIdx.z * sStride;
    dst += (long long)blockIdx.z * dStride;
    __shared__ float tile[32][33];
    int k0 = blockIdx.y * 32, n0 = blockIdx.x * 32;
    int tx = threadIdx.x & 31, ty = threadIdx.x >> 5;  // ty 0..7
    #pragma unroll
    for (int r = ty; r < 32; r += 8) tile[r][tx] = src[(size_t)(k0 + r) * N + n0 + tx];
    __syncthreads();
    #pragma unroll
    for (int r = ty; r < 32; r += 8) dst[(size_t)(n0 + r) * K + k0 + tx] = f2b(tile[tx][r]);
}

// ================= WIDE GEMM: BM x 128 tile (BM=256 or 128), BK=32, 8 waves, 3-ring ====
// BM=256: 72KB LDS -> 2 blocks/CU, 3 loads/stage, vmcnt(3).
// BM=128: 48KB LDS -> 3 blocks/CU, 2 loads/stage, vmcnt(2). Used for under-filled
//         launches (qkv 768=3/CU, oproj+ffn2 512=2/CU, vocab 320) per the fill model:
//         1 block/CU has no inter-block overlap partner (m114 mechanism).
// Counted vmcnt per iter (tile kt landed, kt+1 in flight ACROSS the raw s_barrier).
// STAGE(kt+2) post-barrier overwrites buf[kt-1] whose reads retired pre-barrier.
// 64B-row swizzle: chunk XOR (row>>1)&3 (2-way max = free). XCD swizzle. z = split-K.
// EPI: 1 = bf16 partial (z=0 -> Cout, z=1 -> Cout2); 2 = +bias,relu,bf16;
//      3 = +bias, f32 out [M][Vv] col-guarded (vocab);
//      4 = qkv: RoPE'd q(x0.125)|k -> Cout[M][1024], v-cols -> vt (Cout2) transposed
template<int EPI, int BM>
__global__ __launch_bounds__(512) void k_gemmW(const bf16* __restrict__ A, const bf16* __restrict__ Bt,
                                               void* __restrict__ Cout, void* __restrict__ Cout2,
                                               const float* __restrict__ bias,
                                               const float* __restrict__ cosT, const float* __restrict__ sinT,
                                               int M, int N, int K, int ldA, int ldB) {
    constexpr int PA  = BM / 128;   // A 16B-chunks per thread per stage
    constexpr int NI  = BM / 64;    // i-frags per wave
    constexpr int WRS = BM / 4;     // wave row span
    extern __shared__ __align__(16) char smem[];
    bf16* lAbase = (bf16*)smem;                        // 3 x BM*32
    bf16* lBbase = (bf16*)(smem + 3 * BM * 32 * 2);    // 3 x 128*32

    const int t = threadIdx.x;                 // 0..511
    const int lane = t & 63;
    const int wave = t >> 6;                   // 0..7
    const int wr = wave >> 1, wc = wave & 1;   // 4 x 2 wave grid
    const int l15 = lane & 15, l4 = lane >> 4;

    // XCD swizzle over linearized 3D grid (nwg % 8 == 0 for all launches here)
    const int gx = gridDim.x, gy = gridDim.y;
    const int nwg = gx * gy * gridDim.z;
    const int cpx = nwg >> 3;
    int lin = (blockIdx.z * gy + blockIdx.y) * gx + blockIdx.x;
    lin = (lin & 7) * cpx + (lin >> 3);
    const int bn = lin % gx;
    const int rem = lin / gx;
    const int bm = rem % gy;
    const int bz = rem / gy;

    const bf16* Ab = A + (size_t)(bm * BM) * ldA + (size_t)bz * K;
    const bf16* Bb = Bt + (size_t)(bn * 128) * ldB + (size_t)bz * K;

    // staging maps: 16B chunk q -> row r = q>>2, phys slot s = q&3 holds logical s^((r>>1)&3)
    int soffA[PA], soffB0;
    #pragma unroll
    for (int p = 0; p < PA; p++) {
        int q = p * 512 + t, r = q >> 2, s = q & 3;
        soffA[p] = r * ldA + ((s ^ ((r >> 1) & 3)) << 3);
    }
    {
        int r = t >> 2, s = t & 3;
        soffB0 = r * ldB + ((s ^ ((r >> 1) & 3)) << 3);
    }

    f32x4 acc[NI][4];
    #pragma unroll
    for (int i = 0; i < NI; i++)
        #pragma unroll
        for (int j = 0; j < 4; j++) acc[i][j] = z4();

    auto STAGE = [&](int buf, int kt) {         // PA+1 gload_lds per thread
        const int k0 = kt << 5;
        bf16* la = lAbase + buf * (BM * 32);
        bf16* lb = lBbase + buf * (128 * 32);
        #pragma unroll
        for (int p = 0; p < PA; p++)
            gload_lds16(Ab + (size_t)soffA[p] + k0, &la[(p * 512 + t) * 8]);
        gload_lds16(Bb + (size_t)soffB0 + k0, &lb[t * 8]);
    };

    auto COMPUTE = [&](int buf) {               // one BK=32 slice: NI*4 MFMA/wave
        const char* la = (const char*)(lAbase + buf * (BM * 32));
        const char* lb = (const char*)(lBbase + buf * (128 * 32));
        short8 af[NI], bfr[4];
        #pragma unroll
        for (int i = 0; i < NI; i++) {
            int row = wr * WRS + i * 16 + l15;
            af[i] = *(const short8*)(la + row * 64 + (((l4 ^ (row >> 1)) & 3) << 4));
        }
        #pragma unroll
        for (int j = 0; j < 4; j++) {
            int row = wc * 64 + j * 16 + l15;
            bfr[j] = *(const short8*)(lb + row * 64 + (((l4 ^ (row >> 1)) & 3) << 4));
        }
        #pragma unroll
        for (int i = 0; i < NI; i++)
            #pragma unroll
            for (int j = 0; j < 4; j++)
                acc[i][j] = __builtin_amdgcn_mfma_f32_16x16x32_bf16(af[i], bfr[j], acc[i][j], 0, 0, 0);
    };

    const int nk = K >> 5;
    STAGE(0, 0);
    STAGE(1, 1);
    int kt = 0;
    for (; kt < nk - 1; ++kt) {
        // tile kt landed; kt+1's (PA+1) loads still in flight across the barrier
        if constexpr (PA == 2) asm volatile("s_waitcnt vmcnt(3)" ::: "memory");
        else                   asm volatile("s_waitcnt vmcnt(2)" ::: "memory");
        __builtin_amdgcn_s_barrier();
        if (kt + 2 < nk) STAGE((kt + 2) % 3, kt + 2);
        __builtin_amdgcn_s_setprio(1);
        COMPUTE(kt % 3);
        __builtin_amdgcn_s_setprio(0);
    }
    asm volatile("s_waitcnt vmcnt(0)" ::: "memory");
    __builtin_amdgcn_s_barrier();
    __builtin_amdgcn_s_setprio(1);
    COMPUTE(kt % 3);
    __builtin_amdgcn_s_setprio(0);

    // ---- epilogue ----
    #pragma unroll
    for (int i = 0; i < NI; i++) {
        #pragma unroll
        for (int j = 0; j < 4; j++) {
            const int col = bn * 128 + wc * 64 + j * 16 + l15;
            const int row0 = bm * BM + wr * WRS + i * 16 + l4 * 4;
            if (EPI == 4 && col >= 1024) {
                // v columns -> vt[bh][d][s], 4 consecutive s packed as 8B
                int h = (col - 1024) >> 6, d = (col - 1024) & 63;
                int b = row0 >> 9, s0 = row0 & 511;
                bf16 pk[4];
                #pragma unroll
                for (int r = 0; r < 4; r++) pk[r] = f2b(acc[i][j][r]);
                *(ushort4*)&((bf16*)Cout2)[((size_t)(b * 8 + h) * 64 + d) * 512 + s0] =
                    *(const ushort4*)pk;
                continue;
            }
            #pragma unroll
            for (int r = 0; r < 4; r++) {
                int row = row0 + r;
                float v = acc[i][j][r];
                if (EPI == 1) {
                    bf16* Co = (bf16*)(bz ? Cout2 : Cout);
                    Co[(size_t)row * N + col] = f2b(v);
                } else if (EPI == 2) {
                    v += bias[col];
                    v = v > 0.f ? v : 0.f;
                    ((bf16*)Cout)[(size_t)row * N + col] = f2b(v);
                } else if (EPI == 3) {
                    if (col < Vv) ((float*)Cout)[(size_t)row * Vv + col] = v + bias[col];
                } else {
                    // EPI 4, col < 1024: RoPE on q (scaled 1/8) and k
                    float p = __shfl_xor(v, 1, 64);   // partner column col^1, same row
                    int srow = row & (Sq - 1);
                    int f = (col >> 1) & 31;
                    float cc = cosT[srow * 32 + f], sn = sinT[srow * 32 + f];
                    float o = (col & 1) ? (v * cc + p * sn) : (v * cc - p * sn);
                    if (col < 512) o *= 0.125f;
                    ((bf16*)Cout)[(size_t)row * QKS + col] = f2b(o);
                }
            }
        }
    }
}

// ---------------- causal flash attention: 8 waves x 16 q-rows (QBLK=128), KV tiles of 64 ----
// double-buffered K/V LDS (one raw s_barrier per tile, vmcnt NOT drained -> next tile's
// global loads stay in flight under compute); lP padded to 88; waves skip fully-masked tiles.
__global__ __launch_bounds__(512) void k_attn(const bf16* __restrict__ qkv,
                                              const bf16* __restrict__ vt, bf16* __restrict__ av) {
    __shared__ __align__(16) bf16 lK[2][64][80];
    __shared__ __align__(16) bf16 lV[2][64][80];
    __shared__ __align__(16) bf16 lP[8][16][88];
    const int tq = blockIdx.x, bh = blockIdx.y;
    const int b = bh >> 3, h = bh & 7;
    const int t = threadIdx.x, lane = t & 63, w = t >> 6;   // w 0..7
    const int l15 = lane & 15, l4 = lane >> 4;
    const int q0 = tq * 128;
    const int rowb = q0 + w * 16;                 // wave's first q-row

    short8 qf[2];
    {
        const bf16* qr = qkv + (size_t)(b * Sq + rowb + l15) * QKS + h * 64 + l4 * 8;
        qf[0] = *(const short8*)qr;
        qf[1] = *(const short8*)(qr + 32);
    }
    f32x4 o[4];
    #pragma unroll
    for (int j = 0; j < 4; j++) o[j] = z4();
    float mrow[4] = {-1e30f, -1e30f, -1e30f, -1e30f};
    float ssum[4] = {0.f, 0.f, 0.f, 0.f};

    const int nk = (q0 >> 6) + 2;                 // KV tiles covering rows [q0, q0+128)
    const int sr = t >> 3, scc = (t & 7) * 8;     // 512 threads x 16B = full 64x64 tile
    const bf16* gK = qkv + (size_t)(b * Sq + sr) * QKS + 512 + h * 64 + scc;
    const bf16* gV = vt + (size_t)(bh * 64 + sr) * 512 + scc;
    uint4 rK = *(const uint4*)gK;                 // tile 0 in flight
    uint4 rV = *(const uint4*)gV;

    for (int kt = 0; kt < nk; ++kt) {
        const int buf = kt & 1;
        const int kv0 = kt * 64;
        uint4 nK, nV;
        if (kt + 1 < nk) {                        // issue next tile FIRST (stays in flight
            nK = *(const uint4*)(gK + (size_t)(kt + 1) * 64 * QKS);   //  across the barrier)
            nV = *(const uint4*)(gV + (size_t)(kt + 1) * 64);
        }
        *(uint4*)&lK[buf][sr][scc] = rK;          // compiler waits vmcnt for rK/rV only
        *(uint4*)&lV[buf][sr][scc] = rV;
        asm volatile("s_waitcnt lgkmcnt(0)" ::: "memory");
        __builtin_amdgcn_s_barrier();
        __builtin_amdgcn_sched_barrier(0);

        if (kv0 <= rowb + 15) {                   // wave-uniform: skip fully-masked tiles
            f32x4 sc[4];
            #pragma unroll
            for (int j = 0; j < 4; j++) sc[j] = z4();
            #pragma unroll
            for (int j = 0; j < 4; j++)
                #pragma unroll
                for (int ks = 0; ks < 2; ks++) {
                    short8 kf = *(const short8*)&lK[buf][j * 16 + l15][ks * 32 + l4 * 8];
                    sc[j] = __builtin_amdgcn_mfma_f32_16x16x32_bf16(qf[ks], kf, sc[j], 0, 0, 0);
                }
            if (kv0 + 63 > rowb) {                // some lane-row may violate causality
                #pragma unroll
                for (int j = 0; j < 4; j++)
                    #pragma unroll
                    for (int r = 0; r < 4; r++)
                        if (kv0 + j * 16 + l15 > rowb + l4 * 4 + r) sc[j][r] = -1e30f;
            }
            float corr[4];
            #pragma unroll
            for (int r = 0; r < 4; r++) {
                float m_ = fmaxf(fmaxf(sc[0][r], sc[1][r]), fmaxf(sc[2][r], sc[3][r]));
                #pragma unroll
                for (int d = 1; d < 16; d <<= 1) m_ = fmaxf(m_, __shfl_xor(m_, d, 64));
                float mo = mrow[r];
                float mn = fmaxf(mo, m_);
                mrow[r] = mn;
                corr[r] = __expf(mo - mn);
            }
            float p[4][4];
            #pragma unroll
            for (int j = 0; j < 4; j++)
                #pragma unroll
                for (int r = 0; r < 4; r++)
                    p[j][r] = __expf(sc[j][r] - mrow[r]);
            #pragma unroll
            for (int r = 0; r < 4; r++)
                ssum[r] = ssum[r] * corr[r] + p[0][r] + p[1][r] + p[2][r] + p[3][r];
            #pragma unroll
            for (int j = 0; j < 4; j++)
                #pragma unroll
                for (int r = 0; r < 4; r++)
                    lP[w][l4 * 4 + r][j * 16 + l15] = f2b(p[j][r]);
            #pragma unroll
            for (int j = 0; j < 4; j++) {
                o[j][0] *= corr[0]; o[j][1] *= corr[1]; o[j][2] *= corr[2]; o[j][3] *= corr[3];
            }
            #pragma unroll
            for (int ks = 0; ks < 2; ks++) {
                short8 pa = *(const short8*)&lP[w][l15][ks * 32 + l4 * 8];
                #pragma unroll
                for (int j = 0; j < 4; j++) {
                    short8 vb = *(const short8*)&lV[buf][j * 16 + l15][ks * 32 + l4 * 8];
                    o[j] = __builtin_amdgcn_mfma_f32_16x16x32_bf16(pa, vb, o[j], 0, 0, 0);
                }
            }
        }
        rK = nK; rV = nV;
    }
    #pragma unroll
    for (int r = 0; r < 4; r++) {
        float s = ssum[r];
        #pragma unroll
        for (int d = 1; d < 16; d <<= 1) s += __shfl_xor(s, d, 64);
        ssum[r] = 1.f / s;
    }
    #pragma unroll
    for (int j = 0; j < 4; j++)
        #pragma unroll
        for (int r = 0; r < 4; r++)
            av[(size_t)(b * Sq + rowb + l4 * 4 + r) * 512 + h * 64 + j * 16 + l15] = f2b(o[j][r] * ssum[r]);
}

// -------- h = LN(h + d1 + d2 [+ bias]): bf16 residual, wave-per-row, no LDS ----
template<bool ADDB>
__global__ __launch_bounds__(256) void k_addln(bf16* __restrict__ hb,
                                               const bf16* __restrict__ d1, const bf16* __restrict__ d2,
                                               const float* __restrict__ bias,
                                               const float* __restrict__ gamma, const float* __restrict__ beta) {
    const int lane = threadIdx.x & 63, w = threadIdx.x >> 6;
    const int row = blockIdx.x * 4 + w;
    const size_t base = (size_t)row * Dm + lane * 8;
    float v[8];
    short8 h8 = *(const short8*)&hb[base];
    short8 a8 = *(const short8*)&d1[base];
    short8 b8 = *(const short8*)&d2[base];
    #pragma unroll
    for (int k = 0; k < 8; k++)
        v[k] = bfu((unsigned short)h8[k]) + bfu((unsigned short)a8[k]) + bfu((unsigned short)b8[k]);
    if (ADDB) {
        float4 bb0 = *(const float4*)&bias[lane * 8];
        float4 bb1 = *(const float4*)&bias[lane * 8 + 4];
        v[0] += bb0.x; v[1] += bb0.y; v[2] += bb0.z; v[3] += bb0.w;
        v[4] += bb1.x; v[5] += bb1.y; v[6] += bb1.z; v[7] += bb1.w;
    }
    float s = 0.f, sq = 0.f;
    #pragma unroll
    for (int k = 0; k < 8; k++) { s += v[k]; sq += v[k] * v[k]; }
    #pragma unroll
    for (int m = 1; m < 64; m <<= 1) { s += __shfl_xor(s, m, 64); sq += __shfl_xor(sq, m, 64); }
    float mean = s * (1.f / Dm);
    float var = sq * (1.f / Dm) - mean * mean;
    float inv = rsqrtf(var + 1e-5f);
    float4 g0 = *(const float4*)&gamma[lane * 8];
    float4 g1 = *(const float4*)&gamma[lane * 8 + 4];
    float4 e0 = *(const float4*)&beta[lane * 8];
    float4 e1 = *(const float4*)&beta[lane * 8 + 4];
    float gs[8] = {g0.x, g0.y, g0.z, g0.w, g1.x, g1.y, g1.z, g1.w};
    float es[8] = {e0.x, e0.y, e0.z, e0.w, e1.x, e1.y, e1.z, e1.w};
    short8 ob;
    #pragma unroll
    for (int k = 0; k < 8; k++) {
        float ov = (v[k] - mean) * inv * gs[k] + es[k];
        ob[k] = (short)__bfloat16_as_ushort(f2b(ov));
    }
    *(short8*)&hb[base] = ob;
}

extern "C" void kernel_launch(void* const* d_in, const int* in_sizes, int n_in,
                              void* d_out, int out_size, void* d_ws, size_t ws_size,
                              hipStream_t stream) {
    const int*   data = (const int*)d_in[0];
    const float* emb  = (const float*)d_in[1];
    const float* pos  = (const float*)d_in[2];
    const float* Wq   = (const float*)d_in[3];
    const float* Wkv  = (const float*)d_in[4];
    const float* Wo   = (const float*)d_in[5];
    const float* W1   = (const float*)d_in[6];
    const float* b1   = (const float*)d_in[7];
    const float* W2   = (const float*)d_in[8];
    const float* b2   = (const float*)d_in[9];
    const float* ln1g = (const float*)d_in[10];
    const float* ln1b = (const float*)d_in[11];
    const float* ln2g = (const float*)d_in[12];
    const float* ln2b = (const float*)d_in[13];
    const float* outb = (const float*)d_in[14];
    float* out = (float*)d_out;
    char* ws = (char*)d_ws;

    // dynamic LDS per tile size (idempotent, capture-safe)
    const int WL256 = 3 * (256 * 32 + 128 * 32) * 2;   // 73728
    const int WL128 = 3 * (128 * 32 + 128 * 32) * 2;   // 49152
    (void)hipFuncSetAttribute((const void*)&k_gemmW<1, 128>, hipFuncAttributeMaxDynamicSharedMemorySize, WL128);
    (void)hipFuncSetAttribute((const void*)&k_gemmW<2, 256>, hipFuncAttributeMaxDynamicSharedMemorySize, WL256);
    (void)hipFuncSetAttribute((const void*)&k_gemmW<3, 128>, hipFuncAttributeMaxDynamicSharedMemorySize, WL128);
    (void)hipFuncSetAttribute((const void*)&k_gemmW<4, 128>, hipFuncAttributeMaxDynamicSharedMemorySize, WL128);

    size_t off = 0;
    auto take = [&](size_t bytes) { size_t r = off; off += (bytes + 255) & ~(size_t)255; return r; };
    bf16*  hb    = (bf16*)(ws + take((size_t)Mtok * Dm * 2));
    bf16*  qkvbf = (bf16*)(ws + take((size_t)Mtok * QKS * 2));
    bf16*  vtb   = (bf16*)(ws + take((size_t)Mtok * Dm * 2));
    bf16*  avb   = (bf16*)(ws + take((size_t)Mtok * Dm * 2));
    bf16*  tmpb  = (bf16*)(ws + take((size_t)Mtok * Dm * 2));
    bf16*  tmp2b = (bf16*)(ws + take((size_t)Mtok * Dm * 2));
    bf16*  ff1   = (bf16*)(ws + take((size_t)Mtok * DFFd * 2));
    float* cosT  = (float*)(ws + take((size_t)Sq * 32 * 4));
    float* sinT  = (float*)(ws + take((size_t)Sq * 32 * 4));
    bf16*  embT  = (bf16*)(ws + take((size_t)VPAD * Dm * 2));

    const size_t ofsQKV = 0;                                   // [1536][512]
    const size_t ofsO   = ofsQKV + (size_t)1536 * 512;
    const size_t ofsW1  = ofsO + (size_t)512 * 512;
    const size_t ofsW2  = ofsW1 + (size_t)512 * 2048;
    const size_t SLABE  = ofsW2 + (size_t)2048 * 512;          // 3,145,728 elems

    bf16* wT = (bf16*)(ws + off);
    size_t remain = (ws_size > off) ? (ws_size - off) : 0;
    bool upfront = remain >= SLABE * 12 * 2;

    k_sincos<<<(Sq * 32) / 256, 256, 0, stream>>>(cosT, sinT);
    k_embconv<<<(VPAD * Dm) / 256, 256, 0, stream>>>(emb, embT);
    k_embed<<<Mtok, 256, 0, stream>>>(data, emb, pos, hb);

    if (upfront) {
        k_wtrans<<<dim3(16, 16, 12), 256, 0, stream>>>(Wq,  wT + ofsQKV,             512, 512,  (long long)512 * 512,  (long long)SLABE);
        k_wtrans<<<dim3(32, 16, 12), 256, 0, stream>>>(Wkv, wT + ofsQKV + 512 * 512, 512, 1024, (long long)512 * 1024, (long long)SLABE);
        k_wtrans<<<dim3(16, 16, 12), 256, 0, stream>>>(Wo,  wT + ofsO,  512, 512,  (long long)512 * 512,  (long long)SLABE);
        k_wtrans<<<dim3(64, 16, 12), 256, 0, stream>>>(W1,  wT + ofsW1, 512, 2048, (long long)512 * 2048, (long long)SLABE);
        k_wtrans<<<dim3(16, 64, 12), 256, 0, stream>>>(W2,  wT + ofsW2, 2048, 512, (long long)2048 * 512, (long long)SLABE);
    }

    for (int l = 0; l < Lw; l++) {
        bf16* slab = wT + (upfront ? (size_t)l * SLABE : 0);
        if (!upfront) {
            k_wtrans<<<dim3(16, 16, 1), 256, 0, stream>>>(Wq  + (size_t)l * 512 * 512,  slab + ofsQKV,             512, 512,  0, 0);
            k_wtrans<<<dim3(32, 16, 1), 256, 0, stream>>>(Wkv + (size_t)l * 512 * 1024, slab + ofsQKV + 512 * 512, 512, 1024, 0, 0);
            k_wtrans<<<dim3(16, 16, 1), 256, 0, stream>>>(Wo  + (size_t)l * 512 * 512,  slab + ofsO,  512, 512,  0, 0);
            k_wtrans<<<dim3(64, 16, 1), 256, 0, stream>>>(W1  + (size_t)l * 512 * 2048, slab + ofsW1, 512, 2048, 0, 0);
            k_wtrans<<<dim3(16, 64, 1), 256, 0, stream>>>(W2  + (size_t)l * 2048 * 512, slab + ofsW2, 2048, 512, 0, 0);
        }
        // fused qkv projection: RoPE'd q|k -> qkvbf[M][1024], v -> vtb transposed
        // BM=128 -> 768 blocks = 3/CU exact
        k_gemmW<4, 128><<<dim3(12, 64, 1), 512, WL128, stream>>>(hb, slab + ofsQKV, qkvbf, vtb, nullptr, cosT, sinT,
                                                                 Mtok, 1536, 512, 512, 512);
        // attention (QBLK=128, 8 waves, double-buffered KV)
        k_attn<<<dim3(4, 128), 512, 0, stream>>>(qkvbf, vtb, avb);
        // out proj (bf16 partials, split-K=2; BM=128 -> 512 blocks = 2/CU) + add&LN1
        k_gemmW<1, 128><<<dim3(4, 64, 2), 512, WL128, stream>>>(avb, slab + ofsO, tmpb, tmp2b, nullptr, nullptr, nullptr,
                                                                Mtok, 512, 256, 512, 512);
        k_addln<false><<<Mtok / 4, 256, 0, stream>>>(hb, tmpb, tmp2b, nullptr,
                                                     ln1g + (size_t)l * Dm, ln1b + (size_t)l * Dm);
        // FFN1 (BM=256 -> 512 blocks = 2/CU exact)
        k_gemmW<2, 256><<<dim3(16, 32, 1), 512, WL256, stream>>>(hb, slab + ofsW1, ff1, nullptr, b1 + (size_t)l * DFFd,
                                                                 nullptr, nullptr, Mtok, 2048, 512, 512, 512);
        // FFN2 (split-K=2; BM=128 -> 512 blocks = 2/CU)
        k_gemmW<1, 128><<<dim3(4, 64, 2), 512, WL128, stream>>>(ff1, slab + ofsW2, tmpb, tmp2b, nullptr, nullptr, nullptr,
                                                                Mtok, 512, 1024, 2048, 2048);
        k_addln<true><<<Mtok / 4, 256, 0, stream>>>(hb, tmpb, tmp2b, b2 + (size_t)l * Dm,
                                                    ln2g + (size_t)l * Dm, ln2b + (size_t)l * Dm);
    }
    // final vocab projection -> d_out (f32, col-guarded; BM=128 -> 320 blocks)
    k_gemmW<3, 128><<<dim3(5, 64, 1), 512, WL128, stream>>>(hb, embT, out, nullptr, outb, nullptr, nullptr,
                                                            Mtok, VPAD, 512, 512, 512);
}